// Round 3
// baseline (506.362 us; speedup 1.0000x reference)
//
#include <hip/hip_runtime.h>
#include <hip/hip_bf16.h>

// out[8192,4096] fp32 = x[8192,4096] fp32 @ W[4096,4096] (int8 in int32 container)
// Path: per-row int8 quantize x -> i8 MFMA GEMM (fragment-order LDS staging) -> fp32 scale epilogue.
#define M_DIM 8192
#define N_DIM 4096
#define K_DIM 4096

typedef __attribute__((ext_vector_type(4))) int int4v;
typedef __attribute__((ext_vector_type(8))) short short8;
typedef __attribute__((ext_vector_type(4))) float floatx4;

__device__ __forceinline__ unsigned short f2bf(float f) {
    union { float f; unsigned int u; } cv; cv.f = f;
    unsigned int u = cv.u;
    return (unsigned short)((u + 0x7fffu + ((u >> 16) & 1u)) >> 16);
}

// ---------------- fused pre-pass: x-quant (blocks 0..8191) + W transpose (blocks 8192..12287) ----------------
__global__ __launch_bounds__(256) void prep_kernel(const float* __restrict__ X,
                                                   const int* __restrict__ W,
                                                   char* __restrict__ Xq,
                                                   float* __restrict__ scales,
                                                   char* __restrict__ WT) {
    __shared__ int lds_buf[64 * 17];   // wq: transpose tile (pitch 17, conflict-free). xq: first 4 ints = wave maxes
    const int t = threadIdx.x;

    if (blockIdx.x < M_DIM) {
        // ---- x fp32 -> int8, per-row absmax scale ----
        const int row = blockIdx.x;
        const float4* src = (const float4*)(X + (size_t)row * K_DIM);
        float4 v[4];
        float am = 0.f;
#pragma unroll
        for (int i = 0; i < 4; ++i) {
            v[i] = src[t + i * 256];
            am = fmaxf(am, fmaxf(fmaxf(fabsf(v[i].x), fabsf(v[i].y)),
                                 fmaxf(fabsf(v[i].z), fabsf(v[i].w))));
        }
#pragma unroll
        for (int off = 32; off; off >>= 1) am = fmaxf(am, __shfl_xor(am, off, 64));
        float* wmax = (float*)lds_buf;
        if ((t & 63) == 0) wmax[t >> 6] = am;
        __syncthreads();
        am = fmaxf(fmaxf(wmax[0], wmax[1]), fmaxf(wmax[2], wmax[3]));
        am = fmaxf(am, 1e-20f);
        const float inv = 127.f / am;
        unsigned int* dst = (unsigned int*)(Xq + (size_t)row * K_DIM);
#pragma unroll
        for (int i = 0; i < 4; ++i) {
            int q0 = __float2int_rn(v[i].x * inv);
            int q1 = __float2int_rn(v[i].y * inv);
            int q2 = __float2int_rn(v[i].z * inv);
            int q3 = __float2int_rn(v[i].w * inv);
            dst[t + i * 256] = (unsigned int)(q0 & 255) | ((unsigned int)(q1 & 255) << 8) |
                               ((unsigned int)(q2 & 255) << 16) | ((unsigned int)q3 << 24);
        }
        if (t == 0) scales[row] = am * (1.f / 127.f);
    } else {
        // ---- W int32 [K][N] -> int8 W^T [N][K] ----
        const int idx = blockIdx.x - M_DIM;
        const int tn = idx & 63;       // N/64
        const int tk = idx >> 6;       // K/64
        const int n  = t & 63;
        const int kg = t >> 6;         // 0..3
        int (*trans)[17] = (int (*)[17])lds_buf;

#pragma unroll
        for (int p = 0; p < 4; ++p) {
            const int kb = p * 16 + kg * 4;
            const int* src = W + (size_t)(tk * 64 + kb) * N_DIM + tn * 64 + n;
            int v0 = src[0];
            int v1 = src[N_DIM];
            int v2 = src[2 * N_DIM];
            int v3 = src[3 * N_DIM];
            trans[n][kb >> 2] = (v0 & 255) | ((v1 & 255) << 8) | ((v2 & 255) << 16) |
                                ((unsigned int)v3 << 24);
        }
        __syncthreads();

        const int n2 = t >> 2;
        const int c  = t & 3;
        int o0 = trans[n2][c * 4 + 0];
        int o1 = trans[n2][c * 4 + 1];
        int o2 = trans[n2][c * 4 + 2];
        int o3 = trans[n2][c * 4 + 3];
        char* dst = WT + (size_t)(tn * 64 + n2) * K_DIM + tk * 64 + c * 16;
        int4 o; o.x = o0; o.y = o1; o.z = o2; o.w = o3;
        *(int4*)dst = o;
    }
}

// ---------------- main GEMM: A int8 [M][K], BT int8 [N][K], i8 MFMA ----------------
// LDS tiles stored in MFMA-FRAGMENT ORDER: 16-row block rb at sX + rb*1024, lane l's
// frag bytes at +l*16 (row = l&15, k-chunk = l>>4). Staging lane i fetches exactly that
// element -> frag ds_read_b128 is lane-contiguous (conflict-free), global segments unchanged.
__global__ __launch_bounds__(256) void gemm_i8(const char* __restrict__ A,
                                               const char* __restrict__ BT,
                                               const float* __restrict__ scales,
                                               float* __restrict__ C) {
    __shared__ __attribute__((aligned(16))) char sA[128 * 64];
    __shared__ __attribute__((aligned(16))) char sB[128 * 64];

    const int t    = threadIdx.x;
    const int lane = t & 63;
    const int wave = t >> 6;
    const int bn   = blockIdx.x;   // N/128 = 32
    const int bm   = blockIdx.y;   // M/128 = 64
    const int waveM = (wave >> 1) * 64;
    const int waveN = (wave & 1) * 64;

    // staging: lane i -> row (wave*16 + (i&15)), byte chunk (i>>4)*16  [fragment order]
    const int srow = (wave << 4) + (lane & 15);
    const int schk = (lane >> 4) << 4;
    const char* gA0 = A + (size_t)(bm * 128 + srow) * K_DIM + schk;
    const char* gA1 = gA0 + (size_t)64 * K_DIM;
    const char* gB0 = BT + (size_t)(bn * 128 + srow) * K_DIM + schk;
    const char* gB1 = gB0 + (size_t)64 * K_DIM;
    // wave-uniform LDS dests (HW adds lane*16): row-block (wave) at wave*1024, (+4) at 4096+wave*1024
    char* lA0 = sA + wave * 1024;
    char* lA1 = sA + 4096 + wave * 1024;
    char* lB0 = sB + wave * 1024;
    char* lB1 = sB + 4096 + wave * 1024;

    // fragment reads: a[i] = row block (waveM/16 + i), lane-contiguous
    const char* fA = sA + ((waveM >> 4) << 10) + (lane << 4);
    const char* fB = sB + ((waveN >> 4) << 10) + (lane << 4);

    int4v acc[4][4];
#pragma unroll
    for (int i = 0; i < 4; ++i)
#pragma unroll
        for (int j = 0; j < 4; ++j) acc[i][j] = (int4v){0, 0, 0, 0};

    for (int k0 = 0; k0 < K_DIM; k0 += 64) {
        __builtin_amdgcn_global_load_lds((const __attribute__((address_space(1))) void*)gA0,
                                         (__attribute__((address_space(3))) void*)lA0, 16, 0, 0);
        __builtin_amdgcn_global_load_lds((const __attribute__((address_space(1))) void*)gA1,
                                         (__attribute__((address_space(3))) void*)lA1, 16, 0, 0);
        __builtin_amdgcn_global_load_lds((const __attribute__((address_space(1))) void*)gB0,
                                         (__attribute__((address_space(3))) void*)lB0, 16, 0, 0);
        __builtin_amdgcn_global_load_lds((const __attribute__((address_space(1))) void*)gB1,
                                         (__attribute__((address_space(3))) void*)lB1, 16, 0, 0);
        gA0 += 64; gA1 += 64; gB0 += 64; gB1 += 64;
        __syncthreads();

        int4v a[4], b[4];
#pragma unroll
        for (int i = 0; i < 4; ++i) a[i] = *(const int4v*)(fA + (i << 10));
#pragma unroll
        for (int j = 0; j < 4; ++j) b[j] = *(const int4v*)(fB + (j << 10));
#pragma unroll
        for (int i = 0; i < 4; ++i)
#pragma unroll
            for (int j = 0; j < 4; ++j)
                acc[i][j] = __builtin_amdgcn_mfma_i32_16x16x64_i8(a[i], b[j], acc[i][j], 0, 0, 0);
        __syncthreads();
    }

    // epilogue: C/D layout col=lane&15, row=(lane>>4)*4+reg; out = acc * scale[row]
    const int er = (lane >> 4) << 2;
    const int ec = lane & 15;
#pragma unroll
    for (int i = 0; i < 4; ++i) {
        const size_t row0 = (size_t)(bm * 128 + waveM + i * 16 + er);
        const float4 s4 = *(const float4*)(scales + row0);
        const float sc4[4] = {s4.x, s4.y, s4.z, s4.w};
#pragma unroll
        for (int j = 0; j < 4; ++j) {
            const size_t col = (size_t)(bn * 128 + waveN + j * 16 + ec);
#pragma unroll
            for (int rr = 0; rr < 4; ++rr) {
                C[(row0 + rr) * N_DIM + col] = (float)acc[i][j][rr] * sc4[rr];
            }
        }
    }
}

// ---------------- fallback GEMM (no workspace): bf16, inline-converts x and W ----------------
__global__ __launch_bounds__(256) void gemm_fb(const float* __restrict__ X,
                                               const int* __restrict__ W,
                                               float* __restrict__ C) {
    __shared__ __attribute__((aligned(16))) unsigned short sA[128 * 32];
    __shared__ __attribute__((aligned(16))) unsigned short sB[128 * 32];

    const int t    = threadIdx.x;
    const int lane = t & 63;
    const int wave = t >> 6;
    const int bn   = blockIdx.x;
    const int bm   = blockIdx.y;
    const int waveM = (wave >> 1) * 64;
    const int waveN = (wave & 1) * 64;

    const int ar = t >> 1, ac = (t & 1) << 4;
    const float* gX = X + (size_t)(bm * 128 + ar) * K_DIM + ac;
    const int br = t >> 3, bc = (t & 7) << 4;
    const int* gW = W + (size_t)br * N_DIM + bn * 128 + bc;

    const int fr = lane & 15;
    const int fk = (lane >> 4) << 3;
    const unsigned short* fA = sA + (waveM + fr) * 32 + fk;
    const unsigned short* fB = sB + (waveN + fr) * 32 + fk;

    floatx4 acc[4][4];
#pragma unroll
    for (int i = 0; i < 4; ++i)
#pragma unroll
        for (int j = 0; j < 4; ++j) acc[i][j] = (floatx4){0.f, 0.f, 0.f, 0.f};

    for (int k0 = 0; k0 < K_DIM; k0 += 32) {
        {
            const float4* p = (const float4*)gX;
            float4 v0 = p[0], v1 = p[1], v2 = p[2], v3 = p[3];
            uint4 o0, o1;
            o0.x = (unsigned int)f2bf(v0.x) | ((unsigned int)f2bf(v0.y) << 16);
            o0.y = (unsigned int)f2bf(v0.z) | ((unsigned int)f2bf(v0.w) << 16);
            o0.z = (unsigned int)f2bf(v1.x) | ((unsigned int)f2bf(v1.y) << 16);
            o0.w = (unsigned int)f2bf(v1.z) | ((unsigned int)f2bf(v1.w) << 16);
            o1.x = (unsigned int)f2bf(v2.x) | ((unsigned int)f2bf(v2.y) << 16);
            o1.y = (unsigned int)f2bf(v2.z) | ((unsigned int)f2bf(v2.w) << 16);
            o1.z = (unsigned int)f2bf(v3.x) | ((unsigned int)f2bf(v3.y) << 16);
            o1.w = (unsigned int)f2bf(v3.z) | ((unsigned int)f2bf(v3.w) << 16);
            uint4* d = (uint4*)&sA[ar * 32 + ac];
            d[0] = o0; d[1] = o1;
        }
        {
#pragma unroll
            for (int q = 0; q < 4; ++q) {
                int4 v = ((const int4*)gW)[q];
                sB[(bc + q * 4 + 0) * 32 + br] = f2bf((float)v.x);
                sB[(bc + q * 4 + 1) * 32 + br] = f2bf((float)v.y);
                sB[(bc + q * 4 + 2) * 32 + br] = f2bf((float)v.z);
                sB[(bc + q * 4 + 3) * 32 + br] = f2bf((float)v.w);
            }
        }
        gX += 32;
        gW += (size_t)32 * N_DIM;
        __syncthreads();

        short8 a[4], b[4];
#pragma unroll
        for (int i = 0; i < 4; ++i) a[i] = *(const short8*)(fA + i * 16 * 32);
#pragma unroll
        for (int j = 0; j < 4; ++j) b[j] = *(const short8*)(fB + j * 16 * 32);
#pragma unroll
        for (int i = 0; i < 4; ++i)
#pragma unroll
            for (int j = 0; j < 4; ++j)
                acc[i][j] = __builtin_amdgcn_mfma_f32_16x16x32_bf16(a[i], b[j], acc[i][j], 0, 0, 0);
        __syncthreads();
    }

    const int er = (lane >> 4) << 2;
    const int ec = lane & 15;
#pragma unroll
    for (int i = 0; i < 4; ++i)
#pragma unroll
        for (int j = 0; j < 4; ++j) {
            const size_t row0 = (size_t)(bm * 128 + waveM + i * 16 + er);
            const size_t col  = (size_t)(bn * 128 + waveN + j * 16 + ec);
#pragma unroll
            for (int rr = 0; rr < 4; ++rr) C[(row0 + rr) * N_DIM + col] = acc[i][j][rr];
        }
}

extern "C" void kernel_launch(void* const* d_in, const int* in_sizes, int n_in,
                              void* d_out, int out_size, void* d_ws, size_t ws_size,
                              hipStream_t stream) {
    const float* x = (const float*)d_in[0];
    const int*   w = (const int*)d_in[1];
    float* out = (float*)d_out;

    const size_t bytesXq = (size_t)M_DIM * K_DIM;        // 32 MiB
    const size_t bytesWT = (size_t)K_DIM * N_DIM;        // 16 MiB
    const size_t bytesSc = (size_t)M_DIM * sizeof(float);

    if (ws_size >= bytesXq + bytesWT + bytesSc) {
        char*  Xq = (char*)d_ws;
        char*  WT = (char*)d_ws + bytesXq;
        float* Sc = (float*)((char*)d_ws + bytesXq + bytesWT);
        prep_kernel<<<M_DIM + (N_DIM / 64) * (K_DIM / 64), 256, 0, stream>>>(x, w, Xq, Sc, WT);
        gemm_i8<<<dim3(N_DIM / 128, M_DIM / 128), 256, 0, stream>>>(Xq, WT, Sc, out);
    } else {
        gemm_fb<<<dim3(N_DIM / 128, M_DIM / 128), 256, 0, stream>>>(x, w, out);
    }
}